// Round 14
// baseline (232.859 us; speedup 1.0000x reference)
//
#include <hip/hip_runtime.h>
#include <hip/hip_bf16.h>
#include <math.h>

#define HIDDEN   1024
#define HEADS    16
#define HEAD_DIM 64
#define SEQ      2048
#define BATCH    2
#define FDIM     4096      // 4*HIDDEN
#define MTOT     4096      // BATCH*SEQ
#define MAXSEQ   2048

typedef __bf16 bf16x8 __attribute__((ext_vector_type(8)));
typedef float  f32x4  __attribute__((ext_vector_type(4)));
typedef unsigned short u16;

// fast silu: v_rcp (1 ULP) instead of precise-division sequence
__device__ __forceinline__ float silu_fast(float v) {
    return v * __builtin_amdgcn_rcpf(1.f + __expf(-v));
}

// float -> bf16 (round-to-nearest-even), raw ushort
__device__ __forceinline__ u16 f2bf(float f) {
    union { float f; unsigned u; } v; v.f = f;
    unsigned r = v.u + 0x7FFFu + ((v.u >> 16) & 1u);
    return (u16)(r >> 16);
}
__device__ __forceinline__ float bf2f(u16 b) {
    union { unsigned u; float f; } v; v.u = ((unsigned)b) << 16;
    return v.f;
}
// packed 2xf32 -> 2xbf16 (v_cvt_pk_bf16_f32 on gfx950); low half = a
__device__ __forceinline__ unsigned pk2(float a, float b) {
    union { __hip_bfloat162 h; unsigned u; } z;
    z.h = __float22bfloat162_rn(make_float2(a, b));
    return z.u;
}

// async global->LDS, 16B per lane; LDS dst = wave-uniform base + lane*16
__device__ __forceinline__ void gload16(const void* g, void* l) {
    __builtin_amdgcn_global_load_lds(
        (const __attribute__((address_space(1))) void*)g,
        (__attribute__((address_space(3))) void*)l, 16, 0, 0);
}

// ---------------------------------------------------------------------------
// merged prep kernel: convert X -> Xb (bids 0..2047),
// transpose+convert W1 -> W1t (bids 2048..3071), W2 -> W2t (bids 3072..3327).
// Also zeroes the 8 per-XCD attention ticket counters (re-poison-safe).
// ---------------------------------------------------------------------------
__global__ __launch_bounds__(256) void prep_kernel(
    const float* __restrict__ X, const float* __restrict__ W1,
    const float* __restrict__ W2,
    u16* __restrict__ Xb, u16* __restrict__ W1t, u16* __restrict__ W2t,
    unsigned* __restrict__ ticket)
{
    __shared__ u16 T[64][72];
    const int tid = threadIdx.x;
    const int bid = blockIdx.x;

    if (bid == 0 && tid < 8) ticket[tid] = 0u;

    if (bid < 2048) {
        int idx = (bid * 256 + tid) * 8;
        float4 a = *(const float4*)&X[idx];
        float4 b = *(const float4*)&X[idx + 4];
        uint4 pk = make_uint4(pk2(a.x, a.y), pk2(a.z, a.w),
                              pk2(b.x, b.y), pk2(b.z, b.w));
        *(uint4*)&Xb[idx] = pk;
        return;
    }

    const float* W; u16* Wt; int rows, cols, r0, c0;
    if (bid < 3072) {
        int t = bid - 2048;              // W1: 64 x 16 tiles (cols x rows)
        W = W1; Wt = W1t; rows = HIDDEN; cols = FDIM;
        c0 = (t & 63) * 64; r0 = (t >> 6) * 64;
    } else {
        int t = bid - 3072;              // W2: 16 x 16 tiles
        W = W2; Wt = W2t; rows = HIDDEN; cols = HIDDEN;
        c0 = (t & 15) * 64; r0 = (t >> 4) * 64;
    }
#pragma unroll
    for (int l = 0; l < 4; ++l) {
        int idx = tid + l * 256;
        int row = idx >> 4;
        int c4  = (idx & 15) * 4;
        float4 v = *(const float4*)&W[(size_t)(r0 + row) * cols + c0 + c4];
        T[c4 + 0][row] = f2bf(v.x);
        T[c4 + 1][row] = f2bf(v.y);
        T[c4 + 2][row] = f2bf(v.z);
        T[c4 + 3][row] = f2bf(v.w);
    }
    __syncthreads();
#pragma unroll
    for (int l = 0; l < 2; ++l) {
        int idx = tid + l * 256;
        int row = idx >> 3;          // n-local
        int cb  = (idx & 7) * 8;     // k-local
        *(float4*)&Wt[(size_t)(c0 + row) * rows + r0 + cb] = *(float4*)&T[row][cb];
    }
}

// ---------------------------------------------------------------------------
// bf16 MFMA GEMM core v4 (r13): global_load_lds staging + XOR-swizzled LDS.
// ---------------------------------------------------------------------------
#define GEMM_CORE(A_PTR, BT_PTR, KDIM, BM_, BN_, WMW, WNW)                     \
    enum { MTI = (BM_) / (WMW) / 16, NTI = (BN_) / (WNW) / 16,                 \
           ACH = (BM_) / 8, BCH = (BN_) / 8 };                                 \
    __shared__ __align__(16) u16 As[(BM_) * 64];                               \
    __shared__ __align__(16) u16 Bs[(BN_) * 64];                               \
    const int tid  = threadIdx.x;                                              \
    const int lane = tid & 63;                                                 \
    const int w    = tid >> 6;                                                 \
    const int wm   = w % (WMW), wn = w / (WMW);                                \
    const int l16  = lane & 15, quad = lane >> 4;                              \
    const int m0   = blockIdx.y * (BM_);                                       \
    const int n0   = blockIdx.x * (BN_);                                       \
    const int srow = lane >> 3;                                                \
    const int scol = (((lane & 7) ^ srow)) * 8;   /* swizzled source group */  \
    const int xr   = l16 & 7;                     /* read-side XOR key */      \
    f32x4 acc[MTI][NTI];                                                       \
    _Pragma("unroll")                                                          \
    for (int mt = 0; mt < MTI; ++mt)                                           \
        _Pragma("unroll")                                                      \
        for (int nt = 0; nt < NTI; ++nt)                                       \
            acc[mt][nt] = (f32x4){0.f, 0.f, 0.f, 0.f};                         \
    for (int k0 = 0; k0 < (KDIM); k0 += 64) {                                  \
        __syncthreads();                                                       \
        _Pragma("unroll")                                                      \
        for (int ci = w; ci < ACH; ci += 4) {                                  \
            unsigned off = __builtin_amdgcn_readfirstlane(ci * 1024);          \
            gload16(&(A_PTR)[(size_t)(m0 + ci * 8 + srow) * (KDIM) + k0 + scol],\
                    (char*)As + off);                                          \
        }                                                                      \
        _Pragma("unroll")                                                      \
        for (int ci = w; ci < BCH; ci += 4) {                                  \
            unsigned off = __builtin_amdgcn_readfirstlane(ci * 1024);          \
            gload16(&(BT_PTR)[(size_t)(n0 + ci * 8 + srow) * (KDIM) + k0 + scol],\
                    (char*)Bs + off);                                          \
        }                                                                      \
        __syncthreads();                                                       \
        _Pragma("unroll")                                                      \
        for (int kc = 0; kc < 2; ++kc) {                                       \
            bf16x8 af[MTI], bfr[NTI];                                          \
            const int gsw = ((kc * 4 + quad) ^ xr) * 8;                        \
            _Pragma("unroll")                                                  \
            for (int t = 0; t < MTI; ++t)                                      \
                af[t]  = *(const bf16x8*)&As[(wm * (BM_ / WMW) + t * 16 + l16) \
                                             * 64 + gsw];                      \
            _Pragma("unroll")                                                  \
            for (int t = 0; t < NTI; ++t)                                      \
                bfr[t] = *(const bf16x8*)&Bs[(wn * (BN_ / WNW) + t * 16 + l16) \
                                             * 64 + gsw];                      \
            _Pragma("unroll")                                                  \
            for (int mt = 0; mt < MTI; ++mt)                                   \
                _Pragma("unroll")                                              \
                for (int nt = 0; nt < NTI; ++nt)                               \
                    acc[mt][nt] = __builtin_amdgcn_mfma_f32_16x16x32_bf16(     \
                        bfr[nt], af[mt], acc[mt][nt], 0, 0, 0);                \
        }                                                                      \
    }

// ---------------------------------------------------------------------------
// GEMM1: silu(Xb @ W1t^T + b1) -> Ub / Qh / Kh / Vh (bf16); Q pre-scaled 1/8
// R14: retiled 128x128 -> 64x128 (WMW=1, WNW=4 — gemm2's verified shape).
// Grid (32,64)=2048 blocks; LDS 48->24.6KB (6/CU), acc 16->8 f32x4 (VGPR
// ~100 -> ~5/CU). K-short GEMM (16 K-steps) is latency-bound; every win this
// session came from more resident blocks (R4, R8). Trade: fewer MFMA per
// staged byte — if total flat/worse, revert to R13's 128x128.
// ---------------------------------------------------------------------------
__global__ __launch_bounds__(256) void gemm1_mfma_kernel(
    const u16* __restrict__ A, const u16* __restrict__ Bt,
    const float* __restrict__ b1,
    u16* __restrict__ Ub, u16* __restrict__ Qh,
    u16* __restrict__ Kh, u16* __restrict__ Vh)
{
    GEMM_CORE(A, Bt, HIDDEN, 64, 128, 1, 4)

    const int chunk = n0 >> 10;   // block-uniform: 0=U 1=Q 2=K 3=V
    u16* dstbase = (chunk == 0) ? Ub : (chunk == 1) ? Qh : (chunk == 2) ? Kh : Vh;
    const float postscale = (chunk == 1) ? 0.125f : 1.0f;  // fold QK scale into Q

    float4 bias4[NTI]; int nloc[NTI];
#pragma unroll
    for (int nt = 0; nt < NTI; ++nt) {
        int nb = n0 + wn * 32 + nt * 16 + quad * 4;   // 4 consecutive n
        bias4[nt] = *(const float4*)&b1[nb];
        nloc[nt] = nb & 1023;
    }
#pragma unroll
    for (int mt = 0; mt < MTI; ++mt) {
        int m  = m0 + mt * 16 + l16;           // wm == 0 (WMW=1)
        int bb = m >> 11, s = m & 2047;
#pragma unroll
        for (int nt = 0; nt < NTI; ++nt) {
            float v0 = silu_fast(acc[mt][nt][0] + bias4[nt].x) * postscale;
            float v1 = silu_fast(acc[mt][nt][1] + bias4[nt].y) * postscale;
            float v2 = silu_fast(acc[mt][nt][2] + bias4[nt].z) * postscale;
            float v3 = silu_fast(acc[mt][nt][3] + bias4[nt].w) * postscale;
            uint2 pk = make_uint2(pk2(v0, v1), pk2(v2, v3));
            size_t o;
            if (chunk == 0) {
                o = (size_t)m * 1024 + nloc[nt];
            } else {
                int h = nloc[nt] >> 6, d = nloc[nt] & 63;
                o = (size_t)(((bb * HEADS + h) * SEQ) + s) * HEAD_DIM + d;
            }
            *(uint2*)&dstbase[o] = pk;
        }
    }
}

// ---------------------------------------------------------------------------
// GEMM2: out = G @ W2t^T + b2 (fp32 out). 64x64 tiles (R8): grid 1024 = 4/CU.
// ---------------------------------------------------------------------------
__global__ __launch_bounds__(256) void gemm2_mfma_kernel(
    const u16* __restrict__ A, const u16* __restrict__ Bt,
    const float* __restrict__ b2, float* __restrict__ Out)
{
    GEMM_CORE(A, Bt, HIDDEN, 64, 64, 2, 2)

    float4 bias4[NTI]; int nb[NTI];
#pragma unroll
    for (int nt = 0; nt < NTI; ++nt) {
        nb[nt] = n0 + wn * 32 + nt * 16 + quad * 4;
        bias4[nt] = *(const float4*)&b2[nb[nt]];
    }
#pragma unroll
    for (int mt = 0; mt < MTI; ++mt) {
        int m = m0 + wm * 32 + mt * 16 + l16;
#pragma unroll
        for (int nt = 0; nt < NTI; ++nt) {
            float4 vv;
            vv.x = acc[mt][nt][0] + bias4[nt].x;
            vv.y = acc[mt][nt][1] + bias4[nt].y;
            vv.z = acc[mt][nt][2] + bias4[nt].z;
            vv.w = acc[mt][nt][3] + bias4[nt].w;
            *(float4*)&Out[(size_t)m * 1024 + nb[nt]] = vv;
        }
    }
}

// ---------------------------------------------------------------------------
// MFMA attention v15 (session-best: 68-75us band, FETCH 23MB). UNCHANGED.
//   v8 body (Ps LDS round-trip beats permlane exchange) + per-XCD ticket
//   queues (K/V re-reads are L2 hits). NO setprio (m190 lockstep regime).
//   Grid 768 = 3 blocks/CU co-resident; 1.33 tickets/block dynamic LPT.
// ---------------------------------------------------------------------------
__global__ __launch_bounds__(256, 3) void attn_mfma_kernel(
    const u16* __restrict__ Qh, const u16* __restrict__ Kh,
    const u16* __restrict__ Vh, const float* __restrict__ rel,
    const u16* __restrict__ Ub, u16* __restrict__ G,
    unsigned* __restrict__ ticket)
{
    __shared__ __align__(16) u16 Ks[128][72];
    __shared__ __align__(16) u16 Vt[64][136];    // Vt[d][k], k-width 128
    __shared__ __align__(16) u16 Ps[2][64][64];  // per-parity P, XOR-swizzled
    __shared__ float rel_sh[192];  // i -> delta = (q0 - kp) + i - 127
    __shared__ unsigned sh_t;

    const int tid  = threadIdx.x;
    const int lane = tid & 63;
    const int w    = tid >> 6;
    const int quad = lane >> 4;
    const int l16  = lane & 15;
    const int ws   = w & 1;          // q-half owned by this wave (0 or 1)
    const int pp   = w >> 1;         // chunk parity owned by this wave
    const int qbase = ws * 32;
    const int xk   = l16 & 7;        // Ps swizzle key (qrow&7 == l16&7)
    const int qid  = blockIdx.x & 7; // per-XCD ticket queue

    // staging coords (tile-invariant, block-wide)
    const int k_r = tid >> 3,       k_c = (tid & 7) * 8;
    const int v_k = (tid & 31) * 2, v_d = (tid >> 5) * 8;

    for (;;) {
        if (tid == 0) sh_t = atomicAdd(&ticket[qid], 1u);
        __syncthreads();
        const unsigned t = sh_t;
        if (t >= 128u) return;

        // queue-local LPT decode: heaviest q-tiles first, 4 bh per queue
        const int qt = 31 - (int)(t >> 2);
        const int bh = qid * 4 + (int)(t & 3u);
        const int h  = bh & 15;
        const int bb = bh >> 4;
        const int q0 = qt * 64;

        const u16* Kg = Kh + (size_t)((bb * HEADS + h) * SEQ) * HEAD_DIM;
        const u16* Vg = Vh + (size_t)((bb * HEADS + h) * SEQ) * HEAD_DIM;
        const u16* Qg = Qh + (size_t)((bb * HEADS + h) * SEQ + q0) * HEAD_DIM;

        // Q fragments for this wave's 32 q-rows (2 subtiles of 16)
        bf16x8 qa[2][2];
#pragma unroll
        for (int sub = 0; sub < 2; ++sub) {
            const int qr = qbase + sub * 16 + l16;
            qa[sub][0] = *(const bf16x8*)&Qg[qr * HEAD_DIM + quad * 8];
            qa[sub][1] = *(const bf16x8*)&Qg[qr * HEAD_DIM + 32 + quad * 8];
        }

        // prefetch chunk 0 (and 1 if present) + rel band for pair 0
        float4 kA0 = *(const float4*)&Kg[(size_t)k_r * 64 + k_c];
        float4 kA1 = *(const float4*)&Kg[(size_t)(k_r + 32) * 64 + k_c];
        float4 vA0 = *(const float4*)&Vg[(size_t)v_k * 64 + v_d];
        float4 vA1 = *(const float4*)&Vg[(size_t)(v_k + 1) * 64 + v_d];
        float4 kB0, kB1, vB0, vB1;
        if (qt >= 1) {
            kB0 = *(const float4*)&Kg[(size_t)(64 + k_r) * 64 + k_c];
            kB1 = *(const float4*)&Kg[(size_t)(64 + k_r + 32) * 64 + k_c];
            vB0 = *(const float4*)&Vg[(size_t)(64 + v_k) * 64 + v_d];
            vB1 = *(const float4*)&Vg[(size_t)(64 + v_k + 1) * 64 + v_d];
        }
        float relreg = 0.f;
        if (tid < 191) relreg = rel[(size_t)(q0 + 1920 + tid) * HEADS + h];

        f32x4 o[2][4];   // [q-subtile][dt] — PARTIAL (this wave's parity only)
#pragma unroll
        for (int sub = 0; sub < 2; ++sub)
#pragma unroll
            for (int dt = 0; dt < 4; ++dt) o[sub][dt] = (f32x4){0.f, 0.f, 0.f, 0.f};

        for (int ip = 0; 2 * ip <= qt; ++ip) {
            const int kp = ip * 128;
            const bool hasB = (2 * ip + 1 <= qt);

            // commit staged regs to LDS (block-wide, both chunks)
            *(float4*)&Ks[k_r][k_c]      = kA0;
            *(float4*)&Ks[k_r + 32][k_c] = kA1;
            {
                union { float4 f; u16 u[8]; } a0, a1;
                a0.f = vA0; a1.f = vA1;
#pragma unroll
                for (int i = 0; i < 8; ++i)
                    *(unsigned*)&Vt[v_d + i][v_k] =
                        (unsigned)a0.u[i] | ((unsigned)a1.u[i] << 16);
            }
            if (hasB) {
                *(float4*)&Ks[64 + k_r][k_c]      = kB0;
                *(float4*)&Ks[64 + k_r + 32][k_c] = kB1;
                union { float4 f; u16 u[8]; } a0, a1;
                a0.f = vB0; a1.f = vB1;
#pragma unroll
                for (int i = 0; i < 8; ++i)
                    *(unsigned*)&Vt[v_d + i][64 + v_k] =
                        (unsigned)a0.u[i] | ((unsigned)a1.u[i] << 16);
            }
            if (tid < 191) rel_sh[tid] = relreg;
            __syncthreads();   // barrier A: pair staged

            // prefetch next pair (block-wide)
            {
                const int nk0 = 2 * ip + 2;
                if (nk0 <= qt) {
                    const int b0 = nk0 * 64;
                    kA0 = *(const float4*)&Kg[(size_t)(b0 + k_r) * 64 + k_c];
                    kA1 = *(const float4*)&Kg[(size_t)(b0 + k_r + 32) * 64 + k_c];
                    vA0 = *(const float4*)&Vg[(size_t)(b0 + v_k) * 64 + v_d];
                    vA1 = *(const float4*)&Vg[(size_t)(b0 + v_k + 1) * 64 + v_d];
                    if (tid < 191)
                        relreg = rel[(size_t)(q0 - kp - 128 + 1920 + tid) * HEADS + h];
                    if (nk0 + 1 <= qt) {
                        const int b1 = b0 + 64;
                        kB0 = *(const float4*)&Kg[(size_t)(b1 + k_r) * 64 + k_c];
                        kB1 = *(const float4*)&Kg[(size_t)(b1 + k_r + 32) * 64 + k_c];
                        vB0 = *(const float4*)&Vg[(size_t)(b1 + v_k) * 64 + v_d];
                        vB1 = *(const float4*)&Vg[(size_t)(b1 + v_k + 1) * 64 + v_d];
                    }
                }
            }

            // this wave's chunk of the pair (parity pp)
            const int myc = 2 * ip + pp;       // global chunk index
            if (myc <= qt) {
                const int ko      = pp * 64;   // LDS k-offset
                const int relofs  = pp ? 63 : 127;
                const bool diag   = (myc == qt);
                const int qrelb   = q0 - kp - ko;   // (global q) - (chunk k-base)

                // QK -> silu(+relbias, diag mask) -> Ps (swizzled)
#pragma unroll
                for (int ct = 0; ct < 4; ++ct) {
                    bf16x8 ka0 = *(const bf16x8*)&Ks[ko + ct * 16 + l16][quad * 8];
                    bf16x8 ka1 = *(const bf16x8*)&Ks[ko + ct * 16 + l16][32 + quad * 8];
#pragma unroll
                    for (int sub = 0; sub < 2; ++sub) {
                        f32x4 sc = {0.f, 0.f, 0.f, 0.f};
                        sc = __builtin_amdgcn_mfma_f32_16x16x32_bf16(ka0, qa[sub][0], sc, 0, 0, 0);
                        sc = __builtin_amdgcn_mfma_f32_16x16x32_bf16(ka1, qa[sub][1], sc, 0, 0, 0);
                        const int qrow = qbase + sub * 16 + l16;
                        const int ib   = qrow - ct * 16 - quad * 4 + relofs;
                        float p4[4];
                        if (diag) {
#pragma unroll
                            for (int r = 0; r < 4; ++r) {
                                float s = sc[r] + rel_sh[ib - r];
                                int kloc = ct * 16 + quad * 4 + r;
                                p4[r] = (qrelb + qrow - kloc >= 0) ? silu_fast(s) : 0.f;
                            }
                        } else {
#pragma unroll
                            for (int r = 0; r < 4; ++r) {
                                float s = sc[r] + rel_sh[ib - r];
                                p4[r] = silu_fast(s);
                            }
                        }
                        const int col = (((2 * ct + (quad >> 1)) ^ xk) << 3) + (quad & 1) * 4;
                        *(uint2*)&Ps[pp][qrow][col] =
                            make_uint2(pk2(p4[0], p4[1]), pk2(p4[2], p4[3]));
                    }
                }

                // PV: V fragments read once, used for both q-subtiles
                bf16x8 pa0[2], pa1[2];
#pragma unroll
                for (int sub = 0; sub < 2; ++sub) {
                    const int qrow = qbase + sub * 16 + l16;
                    pa0[sub] = *(const bf16x8*)&Ps[pp][qrow][(quad ^ xk) * 8];
                    pa1[sub] = *(const bf16x8*)&Ps[pp][qrow][((4 + quad) ^ xk) * 8];
                }
#pragma unroll
                for (int dt = 0; dt < 4; ++dt) {
                    bf16x8 vb0 = *(const bf16x8*)&Vt[dt * 16 + l16][ko + quad * 8];
                    bf16x8 vb1 = *(const bf16x8*)&Vt[dt * 16 + l16][ko + 32 + quad * 8];
#pragma unroll
                    for (int sub = 0; sub < 2; ++sub) {
                        o[sub][dt] = __builtin_amdgcn_mfma_f32_16x16x32_bf16(pa0[sub], vb0, o[sub][dt], 0, 0, 0);
                        o[sub][dt] = __builtin_amdgcn_mfma_f32_16x16x32_bf16(pa1[sub], vb1, o[sub][dt], 0, 0, 0);
                    }
                }
            }
            __syncthreads();   // barrier B: reads done before next commit
        }

        // cross-parity o reduction via scratch overlaid on Ks (16KB <= 18432B).
        // Safe: final barrier B guarantees all Ks/Vt/Ps reads are complete.
        float* Ored = (float*)&Ks[0][0];
        if (pp == 1) {
#pragma unroll
            for (int sub = 0; sub < 2; ++sub)
#pragma unroll
                for (int dt = 0; dt < 4; ++dt)
                    *(f32x4*)&Ored[((ws << 3) + (sub << 2) + dt) * 256 + lane * 4] =
                        o[sub][dt];
        }
        __syncthreads();
        if (pp == 0) {
#pragma unroll
            for (int sub = 0; sub < 2; ++sub)
#pragma unroll
                for (int dt = 0; dt < 4; ++dt) {
                    f32x4 r4 = *(const f32x4*)&Ored[((ws << 3) + (sub << 2) + dt) * 256 + lane * 4];
                    o[sub][dt] += r4;
#pragma unroll
                    for (int r = 0; r < 4; ++r) {
                        int q = q0 + qbase + sub * 16 + quad * 4 + r;
                        size_t base = (size_t)(bb * SEQ + q) * HIDDEN +
                                      h * HEAD_DIM + dt * 16 + l16;
                        float u = bf2f(Ub[base]);
                        G[base] = f2bf(o[sub][dt][r] * u);
                    }
                }
        }
        // next-ticket __syncthreads() orders Ored reads before Ks reuse
    }
}

extern "C" void kernel_launch(void* const* d_in, const int* in_sizes, int n_in,
                              void* d_out, int out_size, void* d_ws, size_t ws_size,
                              hipStream_t stream)
{
    const float* X   = (const float*)d_in[0];
    const float* W1  = (const float*)d_in[1];
    const float* b1  = (const float*)d_in[2];
    const float* W2  = (const float*)d_in[3];
    const float* b2  = (const float*)d_in[4];
    const float* rel = (const float*)d_in[5];
    // d_in[6] attn_mask ignored: deterministically causal (tril), applied analytically.
    float* out = (float*)d_out;

    const size_t MH = (size_t)MTOT * HIDDEN;   // 4M elements
    u16* Ub   = (u16*)d_ws;        // 8 MB
    u16* Qh   = Ub  + MH;          // 8 MB
    u16* Kh   = Qh  + MH;          // 8 MB
    u16* Vh   = Kh  + MH;          // 8 MB
    u16* Gbuf = Vh  + MH;          // 8 MB
    u16* Xb   = Gbuf + MH;         // 8 MB
    u16* W1t  = Xb  + MH;          // 8 MB
    u16* W2t  = W1t + MH;          // 2 MB
    unsigned* ticket = (unsigned*)(W2t + (size_t)HIDDEN * HIDDEN);  // 32 B (8 queues)

    prep_kernel<<<3328, 256, 0, stream>>>(X, W1, W2, Xb, W1t, W2t, ticket);
    gemm1_mfma_kernel<<<dim3(FDIM / 128, MTOT / 64), 256, 0, stream>>>(
        Xb, W1t, b1, Ub, Qh, Kh, Vh);
    attn_mfma_kernel<<<dim3(768), 256, 0, stream>>>(
        Qh, Kh, Vh, rel, Ub, Gbuf, ticket);
    gemm2_mfma_kernel<<<dim3(HIDDEN / 64, MTOT / 64), 256, 0, stream>>>(
        Gbuf, W2t, b2, out);
}

// Round 15
// 223.368 us; speedup vs baseline: 1.0425x; 1.0425x over previous
//
#include <hip/hip_runtime.h>
#include <hip/hip_bf16.h>
#include <math.h>

#define HIDDEN   1024
#define HEADS    16
#define HEAD_DIM 64
#define SEQ      2048
#define BATCH    2
#define FDIM     4096      // 4*HIDDEN
#define MTOT     4096      // BATCH*SEQ
#define MAXSEQ   2048

typedef __bf16 bf16x8 __attribute__((ext_vector_type(8)));
typedef float  f32x4  __attribute__((ext_vector_type(4)));
typedef unsigned short u16;

// fast silu: v_rcp (1 ULP) instead of precise-division sequence
__device__ __forceinline__ float silu_fast(float v) {
    return v * __builtin_amdgcn_rcpf(1.f + __expf(-v));
}

// float -> bf16 (round-to-nearest-even), raw ushort
__device__ __forceinline__ u16 f2bf(float f) {
    union { float f; unsigned u; } v; v.f = f;
    unsigned r = v.u + 0x7FFFu + ((v.u >> 16) & 1u);
    return (u16)(r >> 16);
}
__device__ __forceinline__ float bf2f(u16 b) {
    union { unsigned u; float f; } v; v.u = ((unsigned)b) << 16;
    return v.f;
}
// packed 2xf32 -> 2xbf16 (v_cvt_pk_bf16_f32 on gfx950); low half = a
__device__ __forceinline__ unsigned pk2(float a, float b) {
    union { __hip_bfloat162 h; unsigned u; } z;
    z.h = __float22bfloat162_rn(make_float2(a, b));
    return z.u;
}

// async global->LDS, 16B per lane; LDS dst = wave-uniform base + lane*16
__device__ __forceinline__ void gload16(const void* g, void* l) {
    __builtin_amdgcn_global_load_lds(
        (const __attribute__((address_space(1))) void*)g,
        (__attribute__((address_space(3))) void*)l, 16, 0, 0);
}

// ---------------------------------------------------------------------------
// merged prep kernel: convert X -> Xb (bids 0..2047),
// transpose+convert W1 -> W1t (bids 2048..3071), W2 -> W2t (bids 3072..3327).
// Also zeroes the 8 per-XCD attention ticket counters (re-poison-safe).
// ---------------------------------------------------------------------------
__global__ __launch_bounds__(256) void prep_kernel(
    const float* __restrict__ X, const float* __restrict__ W1,
    const float* __restrict__ W2,
    u16* __restrict__ Xb, u16* __restrict__ W1t, u16* __restrict__ W2t,
    unsigned* __restrict__ ticket)
{
    __shared__ u16 T[64][72];
    const int tid = threadIdx.x;
    const int bid = blockIdx.x;

    if (bid == 0 && tid < 8) ticket[tid] = 0u;

    if (bid < 2048) {
        int idx = (bid * 256 + tid) * 8;
        float4 a = *(const float4*)&X[idx];
        float4 b = *(const float4*)&X[idx + 4];
        uint4 pk = make_uint4(pk2(a.x, a.y), pk2(a.z, a.w),
                              pk2(b.x, b.y), pk2(b.z, b.w));
        *(uint4*)&Xb[idx] = pk;
        return;
    }

    const float* W; u16* Wt; int rows, cols, r0, c0;
    if (bid < 3072) {
        int t = bid - 2048;              // W1: 64 x 16 tiles (cols x rows)
        W = W1; Wt = W1t; rows = HIDDEN; cols = FDIM;
        c0 = (t & 63) * 64; r0 = (t >> 6) * 64;
    } else {
        int t = bid - 3072;              // W2: 16 x 16 tiles
        W = W2; Wt = W2t; rows = HIDDEN; cols = HIDDEN;
        c0 = (t & 15) * 64; r0 = (t >> 4) * 64;
    }
#pragma unroll
    for (int l = 0; l < 4; ++l) {
        int idx = tid + l * 256;
        int row = idx >> 4;
        int c4  = (idx & 15) * 4;
        float4 v = *(const float4*)&W[(size_t)(r0 + row) * cols + c0 + c4];
        T[c4 + 0][row] = f2bf(v.x);
        T[c4 + 1][row] = f2bf(v.y);
        T[c4 + 2][row] = f2bf(v.z);
        T[c4 + 3][row] = f2bf(v.w);
    }
    __syncthreads();
#pragma unroll
    for (int l = 0; l < 2; ++l) {
        int idx = tid + l * 256;
        int row = idx >> 3;          // n-local
        int cb  = (idx & 7) * 8;     // k-local
        *(float4*)&Wt[(size_t)(c0 + row) * rows + r0 + cb] = *(float4*)&T[row][cb];
    }
}

// ---------------------------------------------------------------------------
// bf16 MFMA GEMM core v4 (r13): global_load_lds staging + XOR-swizzled LDS.
// ---------------------------------------------------------------------------
#define GEMM_CORE(A_PTR, BT_PTR, KDIM, BM_, BN_, WMW, WNW)                     \
    enum { MTI = (BM_) / (WMW) / 16, NTI = (BN_) / (WNW) / 16,                 \
           ACH = (BM_) / 8, BCH = (BN_) / 8 };                                 \
    __shared__ __align__(16) u16 As[(BM_) * 64];                               \
    __shared__ __align__(16) u16 Bs[(BN_) * 64];                               \
    const int tid  = threadIdx.x;                                              \
    const int lane = tid & 63;                                                 \
    const int w    = tid >> 6;                                                 \
    const int wm   = w % (WMW), wn = w / (WMW);                                \
    const int l16  = lane & 15, quad = lane >> 4;                              \
    const int m0   = blockIdx.y * (BM_);                                       \
    const int n0   = blockIdx.x * (BN_);                                       \
    const int srow = lane >> 3;                                                \
    const int scol = (((lane & 7) ^ srow)) * 8;   /* swizzled source group */  \
    const int xr   = l16 & 7;                     /* read-side XOR key */      \
    f32x4 acc[MTI][NTI];                                                       \
    _Pragma("unroll")                                                          \
    for (int mt = 0; mt < MTI; ++mt)                                           \
        _Pragma("unroll")                                                      \
        for (int nt = 0; nt < NTI; ++nt)                                       \
            acc[mt][nt] = (f32x4){0.f, 0.f, 0.f, 0.f};                         \
    for (int k0 = 0; k0 < (KDIM); k0 += 64) {                                  \
        __syncthreads();                                                       \
        _Pragma("unroll")                                                      \
        for (int ci = w; ci < ACH; ci += 4) {                                  \
            unsigned off = __builtin_amdgcn_readfirstlane(ci * 1024);          \
            gload16(&(A_PTR)[(size_t)(m0 + ci * 8 + srow) * (KDIM) + k0 + scol],\
                    (char*)As + off);                                          \
        }                                                                      \
        _Pragma("unroll")                                                      \
        for (int ci = w; ci < BCH; ci += 4) {                                  \
            unsigned off = __builtin_amdgcn_readfirstlane(ci * 1024);          \
            gload16(&(BT_PTR)[(size_t)(n0 + ci * 8 + srow) * (KDIM) + k0 + scol],\
                    (char*)Bs + off);                                          \
        }                                                                      \
        __syncthreads();                                                       \
        _Pragma("unroll")                                                      \
        for (int kc = 0; kc < 2; ++kc) {                                       \
            bf16x8 af[MTI], bfr[NTI];                                          \
            const int gsw = ((kc * 4 + quad) ^ xr) * 8;                        \
            _Pragma("unroll")                                                  \
            for (int t = 0; t < MTI; ++t)                                      \
                af[t]  = *(const bf16x8*)&As[(wm * (BM_ / WMW) + t * 16 + l16) \
                                             * 64 + gsw];                      \
            _Pragma("unroll")                                                  \
            for (int t = 0; t < NTI; ++t)                                      \
                bfr[t] = *(const bf16x8*)&Bs[(wn * (BN_ / WNW) + t * 16 + l16) \
                                             * 64 + gsw];                      \
            _Pragma("unroll")                                                  \
            for (int mt = 0; mt < MTI; ++mt)                                   \
                _Pragma("unroll")                                              \
                for (int nt = 0; nt < NTI; ++nt)                               \
                    acc[mt][nt] = __builtin_amdgcn_mfma_f32_16x16x32_bf16(     \
                        bfr[nt], af[mt], acc[mt][nt], 0, 0, 0);                \
        }                                                                      \
    }

// ---------------------------------------------------------------------------
// GEMM1: silu(Xb @ W1t^T + b1) -> Ub / Qh / Kh / Vh (bf16); Q pre-scaled 1/8
// 128x128 tiles (R4), grid 1024 = 4 blocks/CU; launch_bounds(256,4) caps
// VGPR at 128 (R11). R14 A/B: 64x128 retile was WORSE (232.9 vs 227.7) —
// staging-efficiency loss canceled the occupancy gain. 128x128 is final.
// R12 lesson: do NOT fuse with attn (register-pressure collapse, 474us).
// ---------------------------------------------------------------------------
__global__ __launch_bounds__(256, 4) void gemm1_mfma_kernel(
    const u16* __restrict__ A, const u16* __restrict__ Bt,
    const float* __restrict__ b1,
    u16* __restrict__ Ub, u16* __restrict__ Qh,
    u16* __restrict__ Kh, u16* __restrict__ Vh)
{
    GEMM_CORE(A, Bt, HIDDEN, 128, 128, 2, 2)

    const int chunk = n0 >> 10;   // block-uniform: 0=U 1=Q 2=K 3=V
    u16* dstbase = (chunk == 0) ? Ub : (chunk == 1) ? Qh : (chunk == 2) ? Kh : Vh;
    const float postscale = (chunk == 1) ? 0.125f : 1.0f;  // fold QK scale into Q

    float4 bias4[NTI]; int nloc[NTI];
#pragma unroll
    for (int nt = 0; nt < NTI; ++nt) {
        int nb = n0 + wn * 64 + nt * 16 + quad * 4;   // 4 consecutive n
        bias4[nt] = *(const float4*)&b1[nb];
        nloc[nt] = nb & 1023;
    }
#pragma unroll
    for (int mt = 0; mt < MTI; ++mt) {
        int m  = m0 + wm * 64 + mt * 16 + l16;
        int bb = m >> 11, s = m & 2047;
#pragma unroll
        for (int nt = 0; nt < NTI; ++nt) {
            float v0 = silu_fast(acc[mt][nt][0] + bias4[nt].x) * postscale;
            float v1 = silu_fast(acc[mt][nt][1] + bias4[nt].y) * postscale;
            float v2 = silu_fast(acc[mt][nt][2] + bias4[nt].z) * postscale;
            float v3 = silu_fast(acc[mt][nt][3] + bias4[nt].w) * postscale;
            uint2 pk = make_uint2(pk2(v0, v1), pk2(v2, v3));
            size_t o;
            if (chunk == 0) {
                o = (size_t)m * 1024 + nloc[nt];
            } else {
                int h = nloc[nt] >> 6, d = nloc[nt] & 63;
                o = (size_t)(((bb * HEADS + h) * SEQ) + s) * HEAD_DIM + d;
            }
            *(uint2*)&dstbase[o] = pk;
        }
    }
}

// ---------------------------------------------------------------------------
// GEMM2: out = G @ W2t^T + b2 (fp32 out). 64x64 tiles (R8): grid 1024 = 4/CU.
// ---------------------------------------------------------------------------
__global__ __launch_bounds__(256) void gemm2_mfma_kernel(
    const u16* __restrict__ A, const u16* __restrict__ Bt,
    const float* __restrict__ b2, float* __restrict__ Out)
{
    GEMM_CORE(A, Bt, HIDDEN, 64, 64, 2, 2)

    float4 bias4[NTI]; int nb[NTI];
#pragma unroll
    for (int nt = 0; nt < NTI; ++nt) {
        nb[nt] = n0 + wn * 32 + nt * 16 + quad * 4;
        bias4[nt] = *(const float4*)&b2[nb[nt]];
    }
#pragma unroll
    for (int mt = 0; mt < MTI; ++mt) {
        int m = m0 + wm * 32 + mt * 16 + l16;
#pragma unroll
        for (int nt = 0; nt < NTI; ++nt) {
            float4 vv;
            vv.x = acc[mt][nt][0] + bias4[nt].x;
            vv.y = acc[mt][nt][1] + bias4[nt].y;
            vv.z = acc[mt][nt][2] + bias4[nt].z;
            vv.w = acc[mt][nt][3] + bias4[nt].w;
            *(float4*)&Out[(size_t)m * 1024 + nb[nt]] = vv;
        }
    }
}

// ---------------------------------------------------------------------------
// MFMA attention v15 (session-best: 68-78us band, FETCH 23MB).
//   v8 body (Ps LDS round-trip beats permlane exchange: the write->read
//   split gives the scheduler independent regions vs 32 serial cross-lane
//   ops) + per-XCD ticket queues (K/V re-reads are L2 hits, -60MB HBM).
//   NO setprio (R9/R10 A/B: -2us in this lockstep-wave structure, m190
//   regime). Grid 768 = 3 blocks/CU co-resident; 1.33 tickets/block for
//   dynamic LPT balance (grid==tickets degenerates, R5).
// ---------------------------------------------------------------------------
__global__ __launch_bounds__(256, 3) void attn_mfma_kernel(
    const u16* __restrict__ Qh, const u16* __restrict__ Kh,
    const u16* __restrict__ Vh, const float* __restrict__ rel,
    const u16* __restrict__ Ub, u16* __restrict__ G,
    unsigned* __restrict__ ticket)
{
    __shared__ __align__(16) u16 Ks[128][72];
    __shared__ __align__(16) u16 Vt[64][136];    // Vt[d][k], k-width 128
    __shared__ __align__(16) u16 Ps[2][64][64];  // per-parity P, XOR-swizzled
    __shared__ float rel_sh[192];  // i -> delta = (q0 - kp) + i - 127
    __shared__ unsigned sh_t;

    const int tid  = threadIdx.x;
    const int lane = tid & 63;
    const int w    = tid >> 6;
    const int quad = lane >> 4;
    const int l16  = lane & 15;
    const int ws   = w & 1;          // q-half owned by this wave (0 or 1)
    const int pp   = w >> 1;         // chunk parity owned by this wave
    const int qbase = ws * 32;
    const int xk   = l16 & 7;        // Ps swizzle key (qrow&7 == l16&7)
    const int qid  = blockIdx.x & 7; // per-XCD ticket queue

    // staging coords (tile-invariant, block-wide)
    const int k_r = tid >> 3,       k_c = (tid & 7) * 8;
    const int v_k = (tid & 31) * 2, v_d = (tid >> 5) * 8;

    for (;;) {
        if (tid == 0) sh_t = atomicAdd(&ticket[qid], 1u);
        __syncthreads();
        const unsigned t = sh_t;
        if (t >= 128u) return;

        // queue-local LPT decode: heaviest q-tiles first, 4 bh per queue
        const int qt = 31 - (int)(t >> 2);
        const int bh = qid * 4 + (int)(t & 3u);
        const int h  = bh & 15;
        const int bb = bh >> 4;
        const int q0 = qt * 64;

        const u16* Kg = Kh + (size_t)((bb * HEADS + h) * SEQ) * HEAD_DIM;
        const u16* Vg = Vh + (size_t)((bb * HEADS + h) * SEQ) * HEAD_DIM;
        const u16* Qg = Qh + (size_t)((bb * HEADS + h) * SEQ + q0) * HEAD_DIM;

        // Q fragments for this wave's 32 q-rows (2 subtiles of 16)
        bf16x8 qa[2][2];
#pragma unroll
        for (int sub = 0; sub < 2; ++sub) {
            const int qr = qbase + sub * 16 + l16;
            qa[sub][0] = *(const bf16x8*)&Qg[qr * HEAD_DIM + quad * 8];
            qa[sub][1] = *(const bf16x8*)&Qg[qr * HEAD_DIM + 32 + quad * 8];
        }

        // prefetch chunk 0 (and 1 if present) + rel band for pair 0
        float4 kA0 = *(const float4*)&Kg[(size_t)k_r * 64 + k_c];
        float4 kA1 = *(const float4*)&Kg[(size_t)(k_r + 32) * 64 + k_c];
        float4 vA0 = *(const float4*)&Vg[(size_t)v_k * 64 + v_d];
        float4 vA1 = *(const float4*)&Vg[(size_t)(v_k + 1) * 64 + v_d];
        float4 kB0, kB1, vB0, vB1;
        if (qt >= 1) {
            kB0 = *(const float4*)&Kg[(size_t)(64 + k_r) * 64 + k_c];
            kB1 = *(const float4*)&Kg[(size_t)(64 + k_r + 32) * 64 + k_c];
            vB0 = *(const float4*)&Vg[(size_t)(64 + v_k) * 64 + v_d];
            vB1 = *(const float4*)&Vg[(size_t)(64 + v_k + 1) * 64 + v_d];
        }
        float relreg = 0.f;
        if (tid < 191) relreg = rel[(size_t)(q0 + 1920 + tid) * HEADS + h];

        f32x4 o[2][4];   // [q-subtile][dt] — PARTIAL (this wave's parity only)
#pragma unroll
        for (int sub = 0; sub < 2; ++sub)
#pragma unroll
            for (int dt = 0; dt < 4; ++dt) o[sub][dt] = (f32x4){0.f, 0.f, 0.f, 0.f};

        for (int ip = 0; 2 * ip <= qt; ++ip) {
            const int kp = ip * 128;
            const bool hasB = (2 * ip + 1 <= qt);

            // commit staged regs to LDS (block-wide, both chunks)
            *(float4*)&Ks[k_r][k_c]      = kA0;
            *(float4*)&Ks[k_r + 32][k_c] = kA1;
            {
                union { float4 f; u16 u[8]; } a0, a1;
                a0.f = vA0; a1.f = vA1;
#pragma unroll
                for (int i = 0; i < 8; ++i)
                    *(unsigned*)&Vt[v_d + i][v_k] =
                        (unsigned)a0.u[i] | ((unsigned)a1.u[i] << 16);
            }
            if (hasB) {
                *(float4*)&Ks[64 + k_r][k_c]      = kB0;
                *(float4*)&Ks[64 + k_r + 32][k_c] = kB1;
                union { float4 f; u16 u[8]; } a0, a1;
                a0.f = vB0; a1.f = vB1;
#pragma unroll
                for (int i = 0; i < 8; ++i)
                    *(unsigned*)&Vt[v_d + i][64 + v_k] =
                        (unsigned)a0.u[i] | ((unsigned)a1.u[i] << 16);
            }
            if (tid < 191) rel_sh[tid] = relreg;
            __syncthreads();   // barrier A: pair staged

            // prefetch next pair (block-wide)
            {
                const int nk0 = 2 * ip + 2;
                if (nk0 <= qt) {
                    const int b0 = nk0 * 64;
                    kA0 = *(const float4*)&Kg[(size_t)(b0 + k_r) * 64 + k_c];
                    kA1 = *(const float4*)&Kg[(size_t)(b0 + k_r + 32) * 64 + k_c];
                    vA0 = *(const float4*)&Vg[(size_t)(b0 + v_k) * 64 + v_d];
                    vA1 = *(const float4*)&Vg[(size_t)(b0 + v_k + 1) * 64 + v_d];
                    if (tid < 191)
                        relreg = rel[(size_t)(q0 - kp - 128 + 1920 + tid) * HEADS + h];
                    if (nk0 + 1 <= qt) {
                        const int b1 = b0 + 64;
                        kB0 = *(const float4*)&Kg[(size_t)(b1 + k_r) * 64 + k_c];
                        kB1 = *(const float4*)&Kg[(size_t)(b1 + k_r + 32) * 64 + k_c];
                        vB0 = *(const float4*)&Vg[(size_t)(b1 + v_k) * 64 + v_d];
                        vB1 = *(const float4*)&Vg[(size_t)(b1 + v_k + 1) * 64 + v_d];
                    }
                }
            }

            // this wave's chunk of the pair (parity pp)
            const int myc = 2 * ip + pp;       // global chunk index
            if (myc <= qt) {
                const int ko      = pp * 64;   // LDS k-offset
                const int relofs  = pp ? 63 : 127;
                const bool diag   = (myc == qt);
                const int qrelb   = q0 - kp - ko;   // (global q) - (chunk k-base)

                // QK -> silu(+relbias, diag mask) -> Ps (swizzled)
#pragma unroll
                for (int ct = 0; ct < 4; ++ct) {
                    bf16x8 ka0 = *(const bf16x8*)&Ks[ko + ct * 16 + l16][quad * 8];
                    bf16x8 ka1 = *(const bf16x8*)&Ks[ko + ct * 16 + l16][32 + quad * 8];
#pragma unroll
                    for (int sub = 0; sub < 2; ++sub) {
                        f32x4 sc = {0.f, 0.f, 0.f, 0.f};
                        sc = __builtin_amdgcn_mfma_f32_16x16x32_bf16(ka0, qa[sub][0], sc, 0, 0, 0);
                        sc = __builtin_amdgcn_mfma_f32_16x16x32_bf16(ka1, qa[sub][1], sc, 0, 0, 0);
                        const int qrow = qbase + sub * 16 + l16;
                        const int ib   = qrow - ct * 16 - quad * 4 + relofs;
                        float p4[4];
                        if (diag) {
#pragma unroll
                            for (int r = 0; r < 4; ++r) {
                                float s = sc[r] + rel_sh[ib - r];
                                int kloc = ct * 16 + quad * 4 + r;
                                p4[r] = (qrelb + qrow - kloc >= 0) ? silu_fast(s) : 0.f;
                            }
                        } else {
#pragma unroll
                            for (int r = 0; r < 4; ++r) {
                                float s = sc[r] + rel_sh[ib - r];
                                p4[r] = silu_fast(s);
                            }
                        }
                        const int col = (((2 * ct + (quad >> 1)) ^ xk) << 3) + (quad & 1) * 4;
                        *(uint2*)&Ps[pp][qrow][col] =
                            make_uint2(pk2(p4[0], p4[1]), pk2(p4[2], p4[3]));
                    }
                }

                // PV: V fragments read once, used for both q-subtiles
                bf16x8 pa0[2], pa1[2];
#pragma unroll
                for (int sub = 0; sub < 2; ++sub) {
                    const int qrow = qbase + sub * 16 + l16;
                    pa0[sub] = *(const bf16x8*)&Ps[pp][qrow][(quad ^ xk) * 8];
                    pa1[sub] = *(const bf16x8*)&Ps[pp][qrow][((4 + quad) ^ xk) * 8];
                }
#pragma unroll
                for (int dt = 0; dt < 4; ++dt) {
                    bf16x8 vb0 = *(const bf16x8*)&Vt[dt * 16 + l16][ko + quad * 8];
                    bf16x8 vb1 = *(const bf16x8*)&Vt[dt * 16 + l16][ko + 32 + quad * 8];
#pragma unroll
                    for (int sub = 0; sub < 2; ++sub) {
                        o[sub][dt] = __builtin_amdgcn_mfma_f32_16x16x32_bf16(pa0[sub], vb0, o[sub][dt], 0, 0, 0);
                        o[sub][dt] = __builtin_amdgcn_mfma_f32_16x16x32_bf16(pa1[sub], vb1, o[sub][dt], 0, 0, 0);
                    }
                }
            }
            __syncthreads();   // barrier B: reads done before next commit
        }

        // cross-parity o reduction via scratch overlaid on Ks (16KB <= 18432B).
        // Safe: final barrier B guarantees all Ks/Vt/Ps reads are complete.
        float* Ored = (float*)&Ks[0][0];
        if (pp == 1) {
#pragma unroll
            for (int sub = 0; sub < 2; ++sub)
#pragma unroll
                for (int dt = 0; dt < 4; ++dt)
                    *(f32x4*)&Ored[((ws << 3) + (sub << 2) + dt) * 256 + lane * 4] =
                        o[sub][dt];
        }
        __syncthreads();
        if (pp == 0) {
#pragma unroll
            for (int sub = 0; sub < 2; ++sub)
#pragma unroll
                for (int dt = 0; dt < 4; ++dt) {
                    f32x4 r4 = *(const f32x4*)&Ored[((ws << 3) + (sub << 2) + dt) * 256 + lane * 4];
                    o[sub][dt] += r4;
#pragma unroll
                    for (int r = 0; r < 4; ++r) {
                        int q = q0 + qbase + sub * 16 + quad * 4 + r;
                        size_t base = (size_t)(bb * SEQ + q) * HIDDEN +
                                      h * HEAD_DIM + dt * 16 + l16;
                        float u = bf2f(Ub[base]);
                        G[base] = f2bf(o[sub][dt][r] * u);
                    }
                }
        }
        // next-ticket __syncthreads() orders Ored reads before Ks reuse
    }
}

extern "C" void kernel_launch(void* const* d_in, const int* in_sizes, int n_in,
                              void* d_out, int out_size, void* d_ws, size_t ws_size,
                              hipStream_t stream)
{
    const float* X   = (const float*)d_in[0];
    const float* W1  = (const float*)d_in[1];
    const float* b1  = (const float*)d_in[2];
    const float* W2  = (const float*)d_in[3];
    const float* b2  = (const float*)d_in[4];
    const float* rel = (const float*)d_in[5];
    // d_in[6] attn_mask ignored: deterministically causal (tril), applied analytically.
    float* out = (float*)d_out;

    const size_t MH = (size_t)MTOT * HIDDEN;   // 4M elements
    u16* Ub   = (u16*)d_ws;        // 8 MB
    u16* Qh   = Ub  + MH;          // 8 MB
    u16* Kh   = Qh  + MH;          // 8 MB
    u16* Vh   = Kh  + MH;          // 8 MB
    u16* Gbuf = Vh  + MH;          // 8 MB
    u16* Xb   = Gbuf + MH;         // 8 MB
    u16* W1t  = Xb  + MH;          // 8 MB
    u16* W2t  = W1t + MH;          // 2 MB
    unsigned* ticket = (unsigned*)(W2t + (size_t)HIDDEN * HIDDEN);  // 32 B (8 queues)

    prep_kernel<<<3328, 256, 0, stream>>>(X, W1, W2, Xb, W1t, W2t, ticket);
    gemm1_mfma_kernel<<<dim3(FDIM / 128, MTOT / 128), 256, 0, stream>>>(
        Xb, W1t, b1, Ub, Qh, Kh, Vh);
    attn_mfma_kernel<<<dim3(768), 256, 0, stream>>>(
        Qh, Kh, Vh, rel, Ub, Gbuf, ticket);
    gemm2_mfma_kernel<<<dim3(HIDDEN / 64, MTOT / 64), 256, 0, stream>>>(
        Gbuf, W2t, b2, out);
}